// Round 2
// baseline (12795.374 us; speedup 1.0000x reference)
//
#include <hip/hip_runtime.h>
#include <hip/hip_bf16.h>
#include <math.h>

// Problem constants
#define BB   64
#define TT   2048
#define DD   8        // LATENT
#define HH   64       // HID
#define LLEN 2046     // length = TT - LAGS
#define NN   (BB*LLEN) // 130944 = 128 * 1023
#define GIN  81       // HID + LAGS*LATENT + 1

// ---------------------------------------------------------------------------
// Generic fused GEMV layer for the embedding MLP (unchanged, passing).
// ---------------------------------------------------------------------------
template<int K, bool ACT>
__device__ __forceinline__ void fwd_layer(float* zr,
                                          const float* __restrict__ W,
                                          const float* __restrict__ bias)
{
    float acc[HH];
#pragma unroll
    for (int j = 0; j < HH; ++j) acc[j] = bias[j];
    for (int k = 0; k < K; ++k) {
        const float zk = zr[k];
        const float* wr = W + k * HH;
#pragma unroll
        for (int j = 0; j < HH; ++j) acc[j] = fmaf(zk, wr[j], acc[j]);
    }
#pragma unroll
    for (int j = 0; j < HH; ++j) {
        float v = acc[j];
        if (ACT) v = (v >= 0.f) ? v : 0.1f * v;
        zr[j] = v;
    }
}

__global__ __launch_bounds__(192) void emb_mlp_kernel(
    const float* __restrict__ emb_in,
    const float* __restrict__ W1, const float* __restrict__ b1,
    const float* __restrict__ Wh, const float* __restrict__ bh,
    const float* __restrict__ W2, const float* __restrict__ b2,
    float* __restrict__ embN)
{
    __shared__ float zrow[192][65];
    const int tid = threadIdx.x;
    const int n = blockIdx.x * 192 + tid;          // 682*192 == NN exact
    const int b = n / LLEN;
    const int l = n - b * LLEN;
    float* zr = zrow[tid];

    const float* ep = emb_in + ((size_t)(b * TT + (l + 2))) * 8;
    {
        float4 e0 = *(const float4*)ep;
        float4 e1 = *(const float4*)(ep + 4);
        zr[0] = e0.x; zr[1] = e0.y; zr[2] = e0.z; zr[3] = e0.w;
        zr[4] = e1.x; zr[5] = e1.y; zr[6] = e1.z; zr[7] = e1.w;
    }

    fwd_layer<8,  true >(zr, W1, b1);
    fwd_layer<HH, true >(zr, Wh,            bh);
    fwd_layer<HH, true >(zr, Wh + HH * HH,  bh + HH);
    fwd_layer<HH, false>(zr, W2, b2);

    float* op = embN + (size_t)n * HH;
#pragma unroll
    for (int j = 0; j < HH; j += 4) {
        float4 v = { zr[j], zr[j+1], zr[j+2], zr[j+3] };
        *(float4*)(op + j) = v;
    }
}

// ---------------------------------------------------------------------------
// gmlp: wave-cooperative. lane = neuron j, 4 samples per wave per group,
// 8 groups per wave, 4 waves per block -> block covers 128 samples.
// Hidden weights (columns) in registers; z/dz broadcast via per-wave LDS.
// ---------------------------------------------------------------------------
__device__ __forceinline__ float wred(float v) {
    v += __shfl_xor(v, 1);  v += __shfl_xor(v, 2);  v += __shfl_xor(v, 4);
    v += __shfl_xor(v, 8);  v += __shfl_xor(v, 16); v += __shfl_xor(v, 32);
    return v;
}

__global__ __launch_bounds__(256, 2) void gmlp_kernel(
    const float* __restrict__ x,
    const float* __restrict__ embN,
    const float* __restrict__ gW1, const float* __restrict__ gb1,
    const float* __restrict__ gWh, const float* __restrict__ gbh,
    const float* __restrict__ gW2, const float* __restrict__ gb2,
    float* __restrict__ resid, float* __restrict__ logd)
{
    __shared__ __align__(16) float w1s[GIN * HH];      // 20736 B
    __shared__ __align__(16) float inbuf[4][GIN * 4];  //  5184 B  [wave][k*4+s]
    __shared__ __align__(16) float bc[4][2][HH * 8];   // 16384 B  [wave][pp][k*8 + (z:0-3,dz:4-7)]

    const int tid  = threadIdx.x;
    const int lane = tid & 63;
    const int w    = tid >> 6;
    const int d    = blockIdx.y;

    // ---- stage per-d L1 weights into LDS ----
    const float* W1g = gW1 + (size_t)d * (GIN * HH);
    for (int i = tid; i < GIN * HH; i += 256) w1s[i] = W1g[i];

    // ---- hidden-layer weight columns into registers (lane j holds W[:,j]) ----
    float wh0[HH], wh1[HH];
    const float* Whg = gWh + (size_t)d * 2 * HH * HH;
#pragma unroll
    for (int k = 0; k < HH; ++k) wh0[k] = Whg[k * HH + lane];
#pragma unroll
    for (int k = 0; k < HH; ++k) wh1[k] = Whg[HH * HH + k * HH + lane];
    const float b1j  = gb1[d * HH + lane];
    const float bh0j = gbh[(d * 2 + 0) * HH + lane];
    const float bh1j = gbh[(d * 2 + 1) * HH + lane];
    const float w2j  = gW2[d * HH + lane];
    const float b2   = gb2[d];

    __syncthreads();   // w1s ready (only sync in the kernel)

    float* ib   = inbuf[w];
    float* bufA = bc[w][0];
    float* bufB = bc[w][1];

    const int xs = lane & 3;    // sample slot this lane stages x for
    const int xk = lane >> 2;   // lag element 0..15

    float e0, e1, e2, e3, xa, xb;
    auto load_grp = [&](int n0) {
        e0 = embN[(size_t)(n0 + 0) * HH + lane];
        e1 = embN[(size_t)(n0 + 1) * HH + lane];
        e2 = embN[(size_t)(n0 + 2) * HH + lane];
        e3 = embN[(size_t)(n0 + 3) * HH + lane];
        const int n = n0 + xs;
        const int b = n / LLEN, l = n - b * LLEN;
        const float* xp = x + ((size_t)(b * TT + l)) * DD;
        xa = xp[xk];                               // lags: x[b,l,0..7],x[b,l+1,0..7]
        xb = (lane < 4) ? xp[16 + d] : 0.f;        // x_t[d] = x[b,l+2,d] (xs==lane, xk==0 here)
    };
    auto write_grp = [&]() {
        float4 ev = { e0, e1, e2, e3 };
        *(float4*)&ib[lane * 4] = ev;              // k = lane (emb part)
        ib[(64 + xk) * 4 + xs] = xa;
        if (lane < 4) ib[320 + lane] = xb;         // k = 80
    };

    const int nbase = blockIdx.x * 128 + w * 32;
    load_grp(nbase);
    write_grp();

    for (int g = 0; g < 8; ++g) {
        const int n0 = nbase + g * 4;
        if (g < 7) load_grp(n0 + 4);               // prefetch next group's inputs

        // ---- L1: 81 -> 64 (forward only) ----
        float f0 = b1j, f1 = b1j, f2 = b1j, f3 = b1j;
#pragma unroll
        for (int k = 0; k < GIN; ++k) {
            const float wv = w1s[k * HH + lane];   // lanes consecutive: free 2-way
            const float4 zq = *(const float4*)&ib[k * 4];  // uniform broadcast
            f0 = fmaf(zq.x, wv, f0);
            f1 = fmaf(zq.y, wv, f1);
            f2 = fmaf(zq.z, wv, f2);
            f3 = fmaf(zq.w, wv, f3);
        }
        if (g < 7) write_grp();                    // L1 done reading ib

        // ---- activation + JVP seed: dz_j = mask_j * W1[80][j] ----
        const float w80 = w1s[80 * HH + lane];
        float m0 = (f0 >= 0.f) ? 1.f : 0.1f;  float z0 = f0 * m0;  float dz0 = w80 * m0;
        float m1 = (f1 >= 0.f) ? 1.f : 0.1f;  float z1 = f1 * m1;  float dz1 = w80 * m1;
        float m2 = (f2 >= 0.f) ? 1.f : 0.1f;  float z2 = f2 * m2;  float dz2 = w80 * m2;
        float m3 = (f3 >= 0.f) ? 1.f : 0.1f;  float z3 = f3 * m3;  float dz3 = w80 * m3;
        {
            float4 zv = { z0, z1, z2, z3 }, dv = { dz0, dz1, dz2, dz3 };
            *(float4*)&bufA[lane * 8]     = zv;
            *(float4*)&bufA[lane * 8 + 4] = dv;
        }

        // ---- H1: fused forward + JVP, weights from registers ----
        f0 = bh0j; f1 = bh0j; f2 = bh0j; f3 = bh0j;
        float j0 = 0.f, j1 = 0.f, j2 = 0.f, j3 = 0.f;
#pragma unroll
        for (int k = 0; k < HH; ++k) {
            const float wv = wh0[k];
            const float4 zq = *(const float4*)&bufA[k * 8];
            const float4 dq = *(const float4*)&bufA[k * 8 + 4];
            f0 = fmaf(zq.x, wv, f0);  j0 = fmaf(dq.x, wv, j0);
            f1 = fmaf(zq.y, wv, f1);  j1 = fmaf(dq.y, wv, j1);
            f2 = fmaf(zq.z, wv, f2);  j2 = fmaf(dq.z, wv, j2);
            f3 = fmaf(zq.w, wv, f3);  j3 = fmaf(dq.w, wv, j3);
        }
        m0 = (f0 >= 0.f) ? 1.f : 0.1f;  z0 = f0 * m0;  dz0 = j0 * m0;
        m1 = (f1 >= 0.f) ? 1.f : 0.1f;  z1 = f1 * m1;  dz1 = j1 * m1;
        m2 = (f2 >= 0.f) ? 1.f : 0.1f;  z2 = f2 * m2;  dz2 = j2 * m2;
        m3 = (f3 >= 0.f) ? 1.f : 0.1f;  z3 = f3 * m3;  dz3 = j3 * m3;
        {
            float4 zv = { z0, z1, z2, z3 }, dv = { dz0, dz1, dz2, dz3 };
            *(float4*)&bufB[lane * 8]     = zv;
            *(float4*)&bufB[lane * 8 + 4] = dv;
        }

        // ---- H2: fused forward + JVP ----
        f0 = bh1j; f1 = bh1j; f2 = bh1j; f3 = bh1j;
        j0 = 0.f; j1 = 0.f; j2 = 0.f; j3 = 0.f;
#pragma unroll
        for (int k = 0; k < HH; ++k) {
            const float wv = wh1[k];
            const float4 zq = *(const float4*)&bufB[k * 8];
            const float4 dq = *(const float4*)&bufB[k * 8 + 4];
            f0 = fmaf(zq.x, wv, f0);  j0 = fmaf(dq.x, wv, j0);
            f1 = fmaf(zq.y, wv, f1);  j1 = fmaf(dq.y, wv, j1);
            f2 = fmaf(zq.z, wv, f2);  j2 = fmaf(dq.z, wv, j2);
            f3 = fmaf(zq.w, wv, f3);  j3 = fmaf(dq.w, wv, j3);
        }
        m0 = (f0 >= 0.f) ? 1.f : 0.1f;  z0 = f0 * m0;  dz0 = j0 * m0;
        m1 = (f1 >= 0.f) ? 1.f : 0.1f;  z1 = f1 * m1;  dz1 = j1 * m1;
        m2 = (f2 >= 0.f) ? 1.f : 0.1f;  z2 = f2 * m2;  dz2 = j2 * m2;
        m3 = (f3 >= 0.f) ? 1.f : 0.1f;  z3 = f3 * m3;  dz3 = j3 * m3;

        // ---- final layer: dot over lanes ----
        const float o0 = wred(z0 * w2j) + b2;  const float q0 = wred(dz0 * w2j);
        const float o1 = wred(z1 * w2j) + b2;  const float q1 = wred(dz1 * w2j);
        const float o2 = wred(z2 * w2j) + b2;  const float q2 = wred(dz2 * w2j);
        const float o3 = wred(z3 * w2j) + b2;  const float q3 = wred(dz3 * w2j);

        if (lane == 0) {
            resid[(size_t)(n0 + 0) * DD + d] = o0;
            resid[(size_t)(n0 + 1) * DD + d] = o1;
            resid[(size_t)(n0 + 2) * DD + d] = o2;
            resid[(size_t)(n0 + 3) * DD + d] = o3;
            logd[(size_t)d * NN + n0 + 0] = logf(fabsf(q0));
            logd[(size_t)d * NN + n0 + 1] = logf(fabsf(q1));
            logd[(size_t)d * NN + n0 + 2] = logf(fabsf(q2));
            logd[(size_t)d * NN + n0 + 3] = logf(fabsf(q3));
        }
    }
}

// ---------------------------------------------------------------------------
// log-det reduction over d
// ---------------------------------------------------------------------------
__global__ __launch_bounds__(256) void reduce_kernel(
    const float* __restrict__ logd, float* __restrict__ out)
{
    const int n = blockIdx.x * 256 + threadIdx.x;
    if (n >= NN) return;
    float s = 0.f;
#pragma unroll
    for (int d = 0; d < DD; ++d) s += logd[(size_t)d * NN + n];
    out[n] = s;
}

extern "C" void kernel_launch(void* const* d_in, const int* in_sizes, int n_in,
                              void* d_out, int out_size, void* d_ws, size_t ws_size,
                              hipStream_t stream)
{
    const float* x          = (const float*)d_in[0];
    const float* embeddings = (const float*)d_in[1];
    const float* fcW1 = (const float*)d_in[2];
    const float* fcb1 = (const float*)d_in[3];
    const float* fcWh = (const float*)d_in[4];
    const float* fcbh = (const float*)d_in[5];
    const float* fcW2 = (const float*)d_in[6];
    const float* fcb2 = (const float*)d_in[7];
    const float* gW1  = (const float*)d_in[8];
    const float* gb1  = (const float*)d_in[9];
    const float* gWh  = (const float*)d_in[10];
    const float* gbh  = (const float*)d_in[11];
    const float* gW2  = (const float*)d_in[12];
    const float* gb2  = (const float*)d_in[13];

    float* out  = (float*)d_out;
    float* embN = (float*)d_ws;                         // NN*64 floats
    float* logd = embN + (size_t)NN * HH;               // NN*8 floats

    emb_mlp_kernel<<<dim3(NN / 192), 192, 0, stream>>>(
        embeddings, fcW1, fcb1, fcWh, fcbh, fcW2, fcb2, embN);

    gmlp_kernel<<<dim3(NN / 128, DD), 256, 0, stream>>>(
        x, embN, gW1, gb1, gWh, gbh, gW2, gb2, out, logd);

    reduce_kernel<<<dim3((NN + 255) / 256), 256, 0, stream>>>(
        logd, out + (size_t)NN * DD);
}

// Round 3
// 1222.904 us; speedup vs baseline: 10.4631x; 10.4631x over previous
//
#include <hip/hip_runtime.h>
#include <hip/hip_bf16.h>
#include <math.h>

// Problem constants
#define BB   64
#define TT   2048
#define DD   8        // LATENT
#define HH   64       // HID
#define LLEN 2046     // length = TT - LAGS
#define NN   (BB*LLEN) // 130944 = 682*192
#define GIN  81       // HID + LAGS*LATENT + 1

#define WAVES 8
#define SPG   8       // samples per group per wave
#define GRP   3       // groups per wave
// block covers WAVES*SPG*GRP = 192 samples; grid.x = NN/192 = 682 exact

// ---------------------------------------------------------------------------
// Embedding MLP (unchanged from round 1 — passing, small share of runtime)
// ---------------------------------------------------------------------------
template<int K, bool ACT>
__device__ __forceinline__ void fwd_layer(float* zr,
                                          const float* __restrict__ W,
                                          const float* __restrict__ bias)
{
    float acc[HH];
#pragma unroll
    for (int j = 0; j < HH; ++j) acc[j] = bias[j];
    for (int k = 0; k < K; ++k) {
        const float zk = zr[k];
        const float* wr = W + k * HH;
#pragma unroll
        for (int j = 0; j < HH; ++j) acc[j] = fmaf(zk, wr[j], acc[j]);
    }
#pragma unroll
    for (int j = 0; j < HH; ++j) {
        float v = acc[j];
        if (ACT) v = (v >= 0.f) ? v : 0.1f * v;
        zr[j] = v;
    }
}

__global__ __launch_bounds__(192) void emb_mlp_kernel(
    const float* __restrict__ emb_in,
    const float* __restrict__ W1, const float* __restrict__ b1,
    const float* __restrict__ Wh, const float* __restrict__ bh,
    const float* __restrict__ W2, const float* __restrict__ b2,
    float* __restrict__ embN)
{
    __shared__ float zrow[192][65];
    const int tid = threadIdx.x;
    const int n = blockIdx.x * 192 + tid;          // 682*192 == NN exact
    const int b = n / LLEN;
    const int l = n - b * LLEN;
    float* zr = zrow[tid];

    const float* ep = emb_in + ((size_t)(b * TT + (l + 2))) * 8;
    {
        float4 e0 = *(const float4*)ep;
        float4 e1 = *(const float4*)(ep + 4);
        zr[0] = e0.x; zr[1] = e0.y; zr[2] = e0.z; zr[3] = e0.w;
        zr[4] = e1.x; zr[5] = e1.y; zr[6] = e1.z; zr[7] = e1.w;
    }

    fwd_layer<8,  true >(zr, W1, b1);
    fwd_layer<HH, true >(zr, Wh,            bh);
    fwd_layer<HH, true >(zr, Wh + HH * HH,  bh + HH);
    fwd_layer<HH, false>(zr, W2, b2);

    float* op = embN + (size_t)n * HH;
#pragma unroll
    for (int j = 0; j < HH; j += 4) {
        float4 v = { zr[j], zr[j+1], zr[j+2], zr[j+3] };
        *(float4*)(op + j) = v;
    }
}

// ---------------------------------------------------------------------------
// gmlp: lane = output neuron j, 8 samples per wave-group, weights in
// block-shared LDS (no big per-thread arrays -> no spill). 8 waves/block,
// no barriers in main loop (per-wave buffers, per-wave in-order LDS).
// ---------------------------------------------------------------------------
__device__ __forceinline__ float wred(float v) {
    v += __shfl_xor(v, 1);  v += __shfl_xor(v, 2);  v += __shfl_xor(v, 4);
    v += __shfl_xor(v, 8);  v += __shfl_xor(v, 16); v += __shfl_xor(v, 32);
    return v;
}

__global__ __launch_bounds__(512, 2) void gmlp_kernel(
    const float* __restrict__ x,
    const float* __restrict__ embN,
    const float* __restrict__ gW1, const float* __restrict__ gb1,
    const float* __restrict__ gWh, const float* __restrict__ gbh,
    const float* __restrict__ gW2, const float* __restrict__ gb2,
    float* __restrict__ resid, float* __restrict__ logd)
{
    __shared__ __align__(16) float w1s[GIN * HH];        // 20736 B
    __shared__ __align__(16) float whs[2 * HH * HH];     // 32768 B
    __shared__ __align__(16) float zin[WAVES][GIN * 8];  // 2592 B/wave
    __shared__ __align__(16) float buf[WAVES][HH * 16];  // 4096 B/wave
    // total: 107008 B -> 1 block/CU, 8 waves/CU (2/SIMD)

    const int tid  = threadIdx.x;
    const int lane = tid & 63;
    const int w    = tid >> 6;
    const int d    = blockIdx.y;

    // ---- stage per-d weights into LDS (coalesced, once per block) ----
    const float* W1g = gW1 + (size_t)d * (GIN * HH);
    for (int i = tid; i < GIN * HH; i += 512) w1s[i] = W1g[i];
    const float* Whg = gWh + (size_t)d * 2 * HH * HH;
    for (int i = tid; i < 2 * HH * HH; i += 512) whs[i] = Whg[i];

    const float b1j  = gb1[d * HH + lane];
    const float bh0j = gbh[(d * 2 + 0) * HH + lane];
    const float bh1j = gbh[(d * 2 + 1) * HH + lane];
    const float w2j  = gW2[d * HH + lane];
    const float b2   = gb2[d];

    __syncthreads();                     // only block-wide sync in the kernel
    const float w80j = w1s[80 * HH + lane];   // JVP seed weight row

    float* zi = zin[w];
    float* bf = buf[w];

    const int si = lane >> 3;            // sample this lane stages lags for
    const int ii = lane & 7;             // element index 0..7

    float e[8], la, lb, lc;
    auto issue_loads = [&](int n0) {
#pragma unroll
        for (int s = 0; s < 8; ++s)
            e[s] = embN[(size_t)(n0 + s) * HH + lane];
        const int n = n0 + si;
        const int b = n / LLEN, l = n - b * LLEN;
        const float* xp = x + ((size_t)(b * TT + l)) * DD;
        la = xp[ii];                     // z[64+ii] = x[b,l,ii]
        lb = xp[8 + ii];                 // z[72+ii] = x[b,l+1,ii]
        lc = xp[16 + d];                 // z[80]    = x[b,l+2,d]
    };
    auto write_zin = [&]() {
        // emb transpose: lane holds z_{k=lane}[s] = e[s]
        float4 q0 = { e[0], e[1], e[2], e[3] };
        float4 q1 = { e[4], e[5], e[6], e[7] };
        *(float4*)&zi[lane * 8]     = q0;
        *(float4*)&zi[lane * 8 + 4] = q1;
        // lag writes: addr dword = 8*ii + si -> 64 distinct dwords, conflict-free
        zi[(64 + ii) * 8 + si] = la;
        zi[(72 + ii) * 8 + si] = lb;
        if (ii == 0) zi[80 * 8 + si] = lc;
    };

    const int wbase = blockIdx.x * (WAVES * SPG * GRP) + w * (SPG * GRP);
    issue_loads(wbase);
    write_zin();

    for (int g = 0; g < GRP; ++g) {
        const int n0 = wbase + g * SPG;
        if (g + 1 < GRP) issue_loads(n0 + SPG);    // prefetch under L1 compute

        // ---- L1: 81 -> 64 (forward only) ----
        float f[8];
#pragma unroll
        for (int s = 0; s < 8; ++s) f[s] = b1j;
#pragma unroll 4
        for (int k = 0; k < GIN; ++k) {
            const float wv = w1s[k * HH + lane];           // 2-way, free
            const float4 a = *(const float4*)&zi[k * 8];   // uniform broadcast
            const float4 c = *(const float4*)&zi[k * 8 + 4];
            f[0] = fmaf(a.x, wv, f[0]);  f[1] = fmaf(a.y, wv, f[1]);
            f[2] = fmaf(a.z, wv, f[2]);  f[3] = fmaf(a.w, wv, f[3]);
            f[4] = fmaf(c.x, wv, f[4]);  f[5] = fmaf(c.y, wv, f[5]);
            f[6] = fmaf(c.z, wv, f[6]);  f[7] = fmaf(c.w, wv, f[7]);
        }

        // activation + JVP seed; publish z/dz to per-wave broadcast buffer
        float z[8], dz[8];
#pragma unroll
        for (int s = 0; s < 8; ++s) {
            const float m = (f[s] >= 0.f) ? 1.f : 0.1f;
            z[s]  = f[s] * m;
            dz[s] = w80j * m;
        }
        {
            float4 q;
            q = { z[0],  z[1],  z[2],  z[3]  };  *(float4*)&bf[lane * 16]      = q;
            q = { z[4],  z[5],  z[6],  z[7]  };  *(float4*)&bf[lane * 16 + 4]  = q;
            q = { dz[0], dz[1], dz[2], dz[3] };  *(float4*)&bf[lane * 16 + 8]  = q;
            q = { dz[4], dz[5], dz[6], dz[7] };  *(float4*)&bf[lane * 16 + 12] = q;
        }
        if (g + 1 < GRP) write_zin();   // zin free after L1 reads (in-order DS)

        // ---- H1 and H2: fused forward + JVP, weights broadcast from LDS ----
#pragma unroll
        for (int hl = 0; hl < 2; ++hl) {
            const float* W = whs + hl * (HH * HH);
            const float bj = hl ? bh1j : bh0j;
            float ff[8], jj[8];
#pragma unroll
            for (int s = 0; s < 8; ++s) { ff[s] = bj; jj[s] = 0.f; }
#pragma unroll 4
            for (int k = 0; k < HH; ++k) {
                const float wv = W[k * HH + lane];
                const float4 az = *(const float4*)&bf[k * 16];
                const float4 cz = *(const float4*)&bf[k * 16 + 4];
                const float4 ad = *(const float4*)&bf[k * 16 + 8];
                const float4 cd = *(const float4*)&bf[k * 16 + 12];
                ff[0] = fmaf(az.x, wv, ff[0]);  jj[0] = fmaf(ad.x, wv, jj[0]);
                ff[1] = fmaf(az.y, wv, ff[1]);  jj[1] = fmaf(ad.y, wv, jj[1]);
                ff[2] = fmaf(az.z, wv, ff[2]);  jj[2] = fmaf(ad.z, wv, jj[2]);
                ff[3] = fmaf(az.w, wv, ff[3]);  jj[3] = fmaf(ad.w, wv, jj[3]);
                ff[4] = fmaf(cz.x, wv, ff[4]);  jj[4] = fmaf(cd.x, wv, jj[4]);
                ff[5] = fmaf(cz.y, wv, ff[5]);  jj[5] = fmaf(cd.y, wv, jj[5]);
                ff[6] = fmaf(cz.z, wv, ff[6]);  jj[6] = fmaf(cd.z, wv, jj[6]);
                ff[7] = fmaf(cz.w, wv, ff[7]);  jj[7] = fmaf(cd.w, wv, jj[7]);
            }
#pragma unroll
            for (int s = 0; s < 8; ++s) {
                const float m = (ff[s] >= 0.f) ? 1.f : 0.1f;
                z[s]  = ff[s] * m;
                dz[s] = jj[s] * m;
            }
            if (hl == 0) {   // republish for H2 (reads done -> safe same-buffer)
                float4 q;
                q = { z[0],  z[1],  z[2],  z[3]  };  *(float4*)&bf[lane * 16]      = q;
                q = { z[4],  z[5],  z[6],  z[7]  };  *(float4*)&bf[lane * 16 + 4]  = q;
                q = { dz[0], dz[1], dz[2], dz[3] };  *(float4*)&bf[lane * 16 + 8]  = q;
                q = { dz[4], dz[5], dz[6], dz[7] };  *(float4*)&bf[lane * 16 + 12] = q;
            }
        }

        // ---- final layer: dot over lanes ----
        float o[8], lq[8];
#pragma unroll
        for (int s = 0; s < 8; ++s) {
            o[s]  = wred(z[s]  * w2j) + b2;
            lq[s] = __logf(fabsf(wred(dz[s] * w2j)));
        }
        if (lane == 0) {
#pragma unroll
            for (int s = 0; s < 8; ++s)
                resid[(size_t)(n0 + s) * DD + d] = o[s];
            float4 q0 = { lq[0], lq[1], lq[2], lq[3] };
            float4 q1 = { lq[4], lq[5], lq[6], lq[7] };
            *(float4*)&logd[(size_t)d * NN + n0]     = q0;
            *(float4*)&logd[(size_t)d * NN + n0 + 4] = q1;
        }
    }
}

// ---------------------------------------------------------------------------
// log-det reduction over d
// ---------------------------------------------------------------------------
__global__ __launch_bounds__(256) void reduce_kernel(
    const float* __restrict__ logd, float* __restrict__ out)
{
    const int n = blockIdx.x * 256 + threadIdx.x;
    if (n >= NN) return;
    float s = 0.f;
#pragma unroll
    for (int d = 0; d < DD; ++d) s += logd[(size_t)d * NN + n];
    out[n] = s;
}

extern "C" void kernel_launch(void* const* d_in, const int* in_sizes, int n_in,
                              void* d_out, int out_size, void* d_ws, size_t ws_size,
                              hipStream_t stream)
{
    const float* x          = (const float*)d_in[0];
    const float* embeddings = (const float*)d_in[1];
    const float* fcW1 = (const float*)d_in[2];
    const float* fcb1 = (const float*)d_in[3];
    const float* fcWh = (const float*)d_in[4];
    const float* fcbh = (const float*)d_in[5];
    const float* fcW2 = (const float*)d_in[6];
    const float* fcb2 = (const float*)d_in[7];
    const float* gW1  = (const float*)d_in[8];
    const float* gb1  = (const float*)d_in[9];
    const float* gWh  = (const float*)d_in[10];
    const float* gbh  = (const float*)d_in[11];
    const float* gW2  = (const float*)d_in[12];
    const float* gb2  = (const float*)d_in[13];

    float* out  = (float*)d_out;
    float* embN = (float*)d_ws;                         // NN*64 floats
    float* logd = embN + (size_t)NN * HH;               // NN*8 floats

    emb_mlp_kernel<<<dim3(NN / 192), 192, 0, stream>>>(
        embeddings, fcW1, fcb1, fcWh, fcbh, fcW2, fcb2, embN);

    gmlp_kernel<<<dim3(NN / (WAVES * SPG * GRP), DD), WAVES * 64, 0, stream>>>(
        x, embN, gW1, gb1, gWh, gbh, gW2, gb2, out, logd);

    reduce_kernel<<<dim3((NN + 255) / 256), 256, 0, stream>>>(
        logd, out + (size_t)NN * DD);
}

// Round 4
// 761.939 us; speedup vs baseline: 16.7932x; 1.6050x over previous
//
#include <hip/hip_runtime.h>
#include <hip/hip_bf16.h>
#include <math.h>

// Problem constants
#define BB   64
#define TT   2048
#define DD   8        // LATENT
#define HH   64       // HID
#define LLEN 2046     // length = TT - LAGS
#define NN   (BB*LLEN) // 130944 = 32*4092
#define GIN  81       // HID + LAGS*LATENT + 1

#define NG   (NN/32)  // 4092 sample-groups of 32
#define WPB  7        // waves per block
#define BPD  585      // blocks per d: 585*7 = 4095 >= 4092
#define ZSTR 36       // padded LDS row stride (dwords, 16B-aligned, swizzle-friendly)

// swizzled LDS offset: row-major [128][ZSTR], s-block slot rotated by row>>3
__device__ __forceinline__ int zoff(int row, int sb) {
    return row * ZSTR + (((sb + (row >> 3)) & 7) << 2);
}

// ---------------------------------------------------------------------------
// Embedding MLP: thread per (b,t); writes embT[g][k][s] (k-major, 32-sample
// groups) so gmlp can stage coalesced without a transpose.
// ---------------------------------------------------------------------------
template<int K, bool ACT>
__device__ __forceinline__ void fwd_layer(float* zr,
                                          const float* __restrict__ W,
                                          const float* __restrict__ bias)
{
    float acc[HH];
#pragma unroll
    for (int j = 0; j < HH; ++j) acc[j] = bias[j];
    for (int k = 0; k < K; ++k) {
        const float zk = zr[k];
        const float* wr = W + k * HH;
#pragma unroll
        for (int j = 0; j < HH; ++j) acc[j] = fmaf(zk, wr[j], acc[j]);
    }
#pragma unroll
    for (int j = 0; j < HH; ++j) {
        float v = acc[j];
        if (ACT) v = (v >= 0.f) ? v : 0.1f * v;
        zr[j] = v;
    }
}

__global__ __launch_bounds__(192) void emb_mlp_kernel(
    const float* __restrict__ emb_in,
    const float* __restrict__ W1, const float* __restrict__ b1,
    const float* __restrict__ Wh, const float* __restrict__ bh,
    const float* __restrict__ W2, const float* __restrict__ b2,
    float* __restrict__ embT)
{
    __shared__ float zrow[192][65];
    const int tid = threadIdx.x;
    const int n = blockIdx.x * 192 + tid;          // 682*192 == NN exact
    const int b = n / LLEN;
    const int l = n - b * LLEN;
    float* zr = zrow[tid];

    const float* ep = emb_in + ((size_t)(b * TT + (l + 2))) * 8;
    {
        float4 e0 = *(const float4*)ep;
        float4 e1 = *(const float4*)(ep + 4);
        zr[0] = e0.x; zr[1] = e0.y; zr[2] = e0.z; zr[3] = e0.w;
        zr[4] = e1.x; zr[5] = e1.y; zr[6] = e1.z; zr[7] = e1.w;
    }

    fwd_layer<8,  true >(zr, W1, b1);
    fwd_layer<HH, true >(zr, Wh,            bh);
    fwd_layer<HH, true >(zr, Wh + HH * HH,  bh + HH);
    fwd_layer<HH, false>(zr, W2, b2);

    // embT[n>>5][k][n&31] — per k, 32 consecutive threads write 128B chunks
    float* op = embT + ((size_t)(n >> 5)) * 2048 + (n & 31);
#pragma unroll
    for (int j = 0; j < HH; ++j) op[j * 32] = zr[j];
}

// ---------------------------------------------------------------------------
// gmlp: one wave = one 32-sample group (for block's d). Lane (sg,jg) owns a
// 4-sample x 8-neuron tile; per k: 1 z-quad + 1 dz-quad from swizzled LDS
// (broadcast, conflict-free) + 2 weight b128; 64 FMA. Wh in LDS, W1 via L1$.
// ---------------------------------------------------------------------------
__global__ __launch_bounds__(WPB * 64, 1) void gmlp_kernel(
    const float* __restrict__ x,
    const float* __restrict__ embT,
    const float* __restrict__ gW1, const float* __restrict__ gb1,
    const float* __restrict__ gWh, const float* __restrict__ gbh,
    const float* __restrict__ gW2, const float* __restrict__ gb2,
    float* __restrict__ resid, float* __restrict__ logd)
{
    __shared__ __align__(16) float whs[2 * HH * HH];        // 32768 B
    __shared__ __align__(16) float zb[WPB][128 * ZSTR];     // 7*18432 B = 129024 B
    // total 161792 B <= 163840 -> 1 block/CU, 7 waves

    const int tid  = threadIdx.x;
    const int lane = tid & 63;
    const int w    = tid >> 6;
    const int d    = blockIdx.x / BPD;
    const int gid  = (blockIdx.x % BPD) * WPB + w;

    // ---- stage hidden weights to LDS (all waves participate, then barrier) ----
    const float* Whg = gWh + (size_t)d * 2 * HH * HH;
    for (int i = tid * 4; i < 2 * HH * HH; i += WPB * 64 * 4)
        *(float4*)&whs[i] = *(const float4*)&Whg[i];
    __syncthreads();
    if (gid >= NG) return;

    float* Z = zb[w];
    const int sg = lane >> 3;   // s-block (4 samples each)
    const int jg = lane & 7;    // j-block (8 neurons each)
    const int n0 = gid * 32;

    // ---- stage emb rows 0..63: coalesced b128, swizzled LDS writes ----
    const float* eb = embT + (size_t)gid * 2048;
#pragma unroll
    for (int i = 0; i < 8; ++i) {
        float4 v = *(const float4*)&eb[i * 256 + lane * 4];
        const int row = i * 8 + (lane >> 3);   // row>>3 == i
        *(float4*)&Z[zoff(row, lane & 7)] = v;
    }
    // ---- stage lag rows 64..79 and x_t row 80 ----
    {
        const int s = lane & 31, h = lane >> 5;
        const int n = n0 + s;
        const int b = n / LLEN, l = n - b * LLEN;
        const float* xp = x + ((size_t)(b * TT + l)) * DD;
        float4 xv0 = *(const float4*)(xp + h * 8);
        float4 xv1 = *(const float4*)(xp + h * 8 + 4);
        float xv[8] = { xv0.x, xv0.y, xv0.z, xv0.w, xv1.x, xv1.y, xv1.z, xv1.w };
#pragma unroll
        for (int r = 0; r < 8; ++r) {
            const int R = 64 + h * 8 + r;
            Z[zoff(R, s >> 2) + (s & 3)] = xv[r];
        }
        if (h == 0) {
            const float xt = xp[16 + d];
            Z[zoff(80, s >> 2) + (s & 3)] = xt;
        }
    }

    // ---- biases / weight bases ----
    const float* W1 = gW1 + (size_t)d * GIN * HH + jg * 8;
    const float4 b1a = *(const float4*)&gb1[d * HH + jg * 8];
    const float4 b1b = *(const float4*)&gb1[d * HH + jg * 8 + 4];

    float f[4][8];
#pragma unroll
    for (int si = 0; si < 4; ++si) {
        f[si][0] = b1a.x; f[si][1] = b1a.y; f[si][2] = b1a.z; f[si][3] = b1a.w;
        f[si][4] = b1b.x; f[si][5] = b1b.y; f[si][6] = b1b.z; f[si][7] = b1b.w;
    }

    // ---- L1: 81 -> 64, forward only ----
#pragma unroll 3
    for (int k = 0; k < GIN; ++k) {
        const float4 wa = *(const float4*)&W1[(size_t)k * HH];
        const float4 wb = *(const float4*)&W1[(size_t)k * HH + 4];
        const float4 zq = *(const float4*)&Z[zoff(k, sg)];
        const float zs[4] = { zq.x, zq.y, zq.z, zq.w };
#pragma unroll
        for (int si = 0; si < 4; ++si) {
            f[si][0] = fmaf(zs[si], wa.x, f[si][0]);
            f[si][1] = fmaf(zs[si], wa.y, f[si][1]);
            f[si][2] = fmaf(zs[si], wa.z, f[si][2]);
            f[si][3] = fmaf(zs[si], wa.w, f[si][3]);
            f[si][4] = fmaf(zs[si], wb.x, f[si][4]);
            f[si][5] = fmaf(zs[si], wb.y, f[si][5]);
            f[si][6] = fmaf(zs[si], wb.z, f[si][6]);
            f[si][7] = fmaf(zs[si], wb.w, f[si][7]);
        }
    }

    // ---- act + JVP seed; transpose-publish z (rows j) and dz (rows 64+j) ----
    {
        const float4 w80a = *(const float4*)&W1[80 * HH];
        const float4 w80b = *(const float4*)&W1[80 * HH + 4];
        const float w80[8] = { w80a.x, w80a.y, w80a.z, w80a.w,
                               w80b.x, w80b.y, w80b.z, w80b.w };
        float zv[4][8], dv[4][8];
#pragma unroll
        for (int si = 0; si < 4; ++si)
#pragma unroll
            for (int jj = 0; jj < 8; ++jj) {
                const float m = (f[si][jj] >= 0.f) ? 1.f : 0.1f;
                zv[si][jj] = f[si][jj] * m;
                dv[si][jj] = w80[jj] * m;
            }
#pragma unroll
        for (int jj = 0; jj < 8; ++jj) {
            const int row = jg * 8 + jj;
            float4 q = { zv[0][jj], zv[1][jj], zv[2][jj], zv[3][jj] };
            *(float4*)&Z[zoff(row, sg)] = q;
            float4 p = { dv[0][jj], dv[1][jj], dv[2][jj], dv[3][jj] };
            *(float4*)&Z[zoff(64 + row, sg)] = p;
        }
    }

    // ---- hidden layers: fused forward + JVP ----
    float ff[4][8], dd[4][8];
#pragma unroll
    for (int hl = 0; hl < 2; ++hl) {
        const float* Wl = whs + hl * (HH * HH) + jg * 8;
        const float4 ba = *(const float4*)&gbh[(d * 2 + hl) * HH + jg * 8];
        const float4 bb = *(const float4*)&gbh[(d * 2 + hl) * HH + jg * 8 + 4];
#pragma unroll
        for (int si = 0; si < 4; ++si) {
            ff[si][0] = ba.x; ff[si][1] = ba.y; ff[si][2] = ba.z; ff[si][3] = ba.w;
            ff[si][4] = bb.x; ff[si][5] = bb.y; ff[si][6] = bb.z; ff[si][7] = bb.w;
#pragma unroll
            for (int jj = 0; jj < 8; ++jj) dd[si][jj] = 0.f;
        }
#pragma unroll 2
        for (int k = 0; k < HH; ++k) {
            const float4 wa = *(const float4*)&Wl[k * HH];
            const float4 wb = *(const float4*)&Wl[k * HH + 4];
            const float4 zq = *(const float4*)&Z[zoff(k, sg)];
            const float4 dq = *(const float4*)&Z[zoff(64 + k, sg)];
            const float zs[4] = { zq.x, zq.y, zq.z, zq.w };
            const float ds[4] = { dq.x, dq.y, dq.z, dq.w };
#pragma unroll
            for (int si = 0; si < 4; ++si) {
                ff[si][0] = fmaf(zs[si], wa.x, ff[si][0]);  dd[si][0] = fmaf(ds[si], wa.x, dd[si][0]);
                ff[si][1] = fmaf(zs[si], wa.y, ff[si][1]);  dd[si][1] = fmaf(ds[si], wa.y, dd[si][1]);
                ff[si][2] = fmaf(zs[si], wa.z, ff[si][2]);  dd[si][2] = fmaf(ds[si], wa.z, dd[si][2]);
                ff[si][3] = fmaf(zs[si], wa.w, ff[si][3]);  dd[si][3] = fmaf(ds[si], wa.w, dd[si][3]);
                ff[si][4] = fmaf(zs[si], wb.x, ff[si][4]);  dd[si][4] = fmaf(ds[si], wb.x, dd[si][4]);
                ff[si][5] = fmaf(zs[si], wb.y, ff[si][5]);  dd[si][5] = fmaf(ds[si], wb.y, dd[si][5]);
                ff[si][6] = fmaf(zs[si], wb.z, ff[si][6]);  dd[si][6] = fmaf(ds[si], wb.z, dd[si][6]);
                ff[si][7] = fmaf(zs[si], wb.w, ff[si][7]);  dd[si][7] = fmaf(ds[si], wb.w, dd[si][7]);
            }
        }
        // activation (in place)
#pragma unroll
        for (int si = 0; si < 4; ++si)
#pragma unroll
            for (int jj = 0; jj < 8; ++jj) {
                const float m = (ff[si][jj] >= 0.f) ? 1.f : 0.1f;
                ff[si][jj] *= m;
                dd[si][jj] *= m;
            }
        if (hl == 0) {   // republish for H2 (all reads of this buffer are done)
#pragma unroll
            for (int jj = 0; jj < 8; ++jj) {
                const int row = jg * 8 + jj;
                float4 q = { ff[0][jj], ff[1][jj], ff[2][jj], ff[3][jj] };
                *(float4*)&Z[zoff(row, sg)] = q;
                float4 p = { dd[0][jj], dd[1][jj], dd[2][jj], dd[3][jj] };
                *(float4*)&Z[zoff(64 + row, sg)] = p;
            }
        }
    }

    // ---- final layer: 64 -> 1 (reduce over jg lanes) ----
    {
        const float4 w2a = *(const float4*)&gW2[d * HH + jg * 8];
        const float4 w2b = *(const float4*)&gW2[d * HH + jg * 8 + 4];
        const float b2 = gb2[d];
        float o[4], q[4];
#pragma unroll
        for (int si = 0; si < 4; ++si) {
            o[si] = ff[si][0]*w2a.x + ff[si][1]*w2a.y + ff[si][2]*w2a.z + ff[si][3]*w2a.w
                  + ff[si][4]*w2b.x + ff[si][5]*w2b.y + ff[si][6]*w2b.z + ff[si][7]*w2b.w;
            q[si] = dd[si][0]*w2a.x + dd[si][1]*w2a.y + dd[si][2]*w2a.z + dd[si][3]*w2a.w
                  + dd[si][4]*w2b.x + dd[si][5]*w2b.y + dd[si][6]*w2b.z + dd[si][7]*w2b.w;
#pragma unroll
            for (int m = 1; m <= 4; m <<= 1) {
                o[si] += __shfl_xor(o[si], m);
                q[si] += __shfl_xor(q[si], m);
            }
        }
        if (jg == 0) {
            const int nb = n0 + sg * 4;
            float4 lq;
            lq.x = __logf(fabsf(q[0])); lq.y = __logf(fabsf(q[1]));
            lq.z = __logf(fabsf(q[2])); lq.w = __logf(fabsf(q[3]));
#pragma unroll
            for (int si = 0; si < 4; ++si)
                resid[(size_t)(nb + si) * DD + d] = o[si] + b2;
            *(float4*)&logd[(size_t)d * NN + nb] = lq;
        }
    }
}

// ---------------------------------------------------------------------------
// log-det reduction over d
// ---------------------------------------------------------------------------
__global__ __launch_bounds__(256) void reduce_kernel(
    const float* __restrict__ logd, float* __restrict__ out)
{
    const int n = blockIdx.x * 256 + threadIdx.x;
    if (n >= NN) return;
    float s = 0.f;
#pragma unroll
    for (int d = 0; d < DD; ++d) s += logd[(size_t)d * NN + n];
    out[n] = s;
}

extern "C" void kernel_launch(void* const* d_in, const int* in_sizes, int n_in,
                              void* d_out, int out_size, void* d_ws, size_t ws_size,
                              hipStream_t stream)
{
    const float* x          = (const float*)d_in[0];
    const float* embeddings = (const float*)d_in[1];
    const float* fcW1 = (const float*)d_in[2];
    const float* fcb1 = (const float*)d_in[3];
    const float* fcWh = (const float*)d_in[4];
    const float* fcbh = (const float*)d_in[5];
    const float* fcW2 = (const float*)d_in[6];
    const float* fcb2 = (const float*)d_in[7];
    const float* gW1  = (const float*)d_in[8];
    const float* gb1  = (const float*)d_in[9];
    const float* gWh  = (const float*)d_in[10];
    const float* gbh  = (const float*)d_in[11];
    const float* gW2  = (const float*)d_in[12];
    const float* gb2  = (const float*)d_in[13];

    float* out  = (float*)d_out;
    float* embT = (float*)d_ws;                         // NN*64 floats (k-major groups)
    float* logd = embT + (size_t)NN * HH;               // NN*8 floats

    emb_mlp_kernel<<<dim3(NN / 192), 192, 0, stream>>>(
        embeddings, fcW1, fcb1, fcWh, fcbh, fcW2, fcb2, embT);

    gmlp_kernel<<<dim3(BPD * DD), WPB * 64, 0, stream>>>(
        x, embT, gW1, gb1, gWh, gbh, gW2, gb2, out, logd);

    reduce_kernel<<<dim3((NN + 255) / 256), 256, 0, stream>>>(
        logd, out + (size_t)NN * DD);
}